// Round 1
// baseline (401.338 us; speedup 1.0000x reference)
//
#include <hip/hip_runtime.h>
#include <hip/hip_bf16.h>

typedef __attribute__((ext_vector_type(8))) short short8;
typedef __attribute__((ext_vector_type(4))) short short4v;
typedef __attribute__((ext_vector_type(4))) float floatx4;

#define NND 8192
#define DHID 512
#define TAU_INV 2.0f
// log2(e)/tau
#define CEXP 2.885390081777927f
#define E2 7.389056098930650f

__device__ inline unsigned short f2bf(float f) {
    union { float f; unsigned u; } v; v.f = f;
    unsigned r = v.u + 0x7FFFu + ((v.u >> 16) & 1u);
    return (unsigned short)(r >> 16);
}
__device__ inline float bf2f(short s) {
    union { unsigned u; float f; } v; v.u = ((unsigned)(unsigned short)s) << 16;
    return v.f;
}

// ---------------- cast / transpose helpers ----------------

__global__ void cast_bf16(const float* __restrict__ in, short* __restrict__ out) {
    int i = blockIdx.x * 256 + threadIdx.x;   // one thread = 8 elems
    floatx4 v0 = ((const floatx4*)in)[2 * i];
    floatx4 v1 = ((const floatx4*)in)[2 * i + 1];
    short8 o;
    o[0] = (short)f2bf(v0[0]); o[1] = (short)f2bf(v0[1]);
    o[2] = (short)f2bf(v0[2]); o[3] = (short)f2bf(v0[3]);
    o[4] = (short)f2bf(v1[0]); o[5] = (short)f2bf(v1[1]);
    o[6] = (short)f2bf(v1[2]); o[7] = (short)f2bf(v1[3]);
    ((short8*)out)[i] = o;
}

// in: [K=512][N=512] row-major; out[n][k] = in[k][n]  (bf16, N x K layout)
__global__ void transpose_cast(const float* __restrict__ in, short* __restrict__ out) {
    int idx = blockIdx.x * 256 + threadIdx.x;
    int n = idx >> 9, k = idx & 511;
    out[(n << 9) + k] = (short)f2bf(in[(k << 9) + n]);
}

// ---------------- fused GEMM (NT): C = A[M,512] * B[N,512]^T ----------------
// MODE 0: +bias, elu, -> bf16 out      (projection layer 1)
// MODE 1: +bias        -> fp32 out     (projection layer 2)
// MODE 2: exp2(c*CEXP) -> atomic row sums (+ col sums if WANT_COL)
#define BM 128
#define BN 128
#define BK 32
#define LDSP 40   // padded row stride (elems): 80B rows -> ~2-way bank aliasing (free)

template<int MODE, bool WANT_COL>
__global__ __launch_bounds__(256, 2)
void gemm_nt(const short* __restrict__ A, const short* __restrict__ B, int N,
             const float* __restrict__ bias,
             short* __restrict__ outBf, float* __restrict__ outF,
             float* __restrict__ rowsum, float* __restrict__ colsum)
{
    __shared__ short As[BM * LDSP];
    __shared__ short Bs[BN * LDSP];

    const int tid  = threadIdx.x;
    const int m0   = blockIdx.x * BM;
    const int n0   = blockIdx.y * BN;
    const int wave = tid >> 6;
    const int lane = tid & 63;
    const int wr   = wave >> 1;        // 0..1 : wave row
    const int wc   = wave & 1;         // 0..1 : wave col
    const int lrow = lane & 15;
    const int lk   = lane >> 4;        // 0..3

    // staging coords: 16B chunk c = pass*256 + tid ; row = c>>2, col = (c&3)*8
    const int r0 = tid >> 2;
    const int c0 = (tid & 3) * 8;

    floatx4 acc[4][4];
    floatx4 zero4 = {0.f, 0.f, 0.f, 0.f};
#pragma unroll
    for (int m = 0; m < 4; ++m)
#pragma unroll
        for (int n = 0; n < 4; ++n) acc[m][n] = zero4;

    for (int kt = 0; kt < 512 / BK; ++kt) {
        const int k0 = kt * BK;
        short8 a0 = *(const short8*)(A + (size_t)(m0 + r0) * 512 + k0 + c0);
        short8 a1 = *(const short8*)(A + (size_t)(m0 + 64 + r0) * 512 + k0 + c0);
        short8 b0 = *(const short8*)(B + (size_t)(n0 + r0) * 512 + k0 + c0);
        short8 b1 = *(const short8*)(B + (size_t)(n0 + 64 + r0) * 512 + k0 + c0);
        __syncthreads();   // previous iteration's LDS reads done
        *(short8*)(&As[r0 * LDSP + c0])        = a0;
        *(short8*)(&As[(r0 + 64) * LDSP + c0]) = a1;
        *(short8*)(&Bs[r0 * LDSP + c0])        = b0;
        *(short8*)(&Bs[(r0 + 64) * LDSP + c0]) = b1;
        __syncthreads();
        short8 fa[4], fb[4];
#pragma unroll
        for (int m = 0; m < 4; ++m)
            fa[m] = *(const short8*)(&As[(wr * 64 + m * 16 + lrow) * LDSP + lk * 8]);
#pragma unroll
        for (int n = 0; n < 4; ++n)
            fb[n] = *(const short8*)(&Bs[(wc * 64 + n * 16 + lrow) * LDSP + lk * 8]);
#pragma unroll
        for (int m = 0; m < 4; ++m)
#pragma unroll
            for (int n = 0; n < 4; ++n)
                acc[m][n] = __builtin_amdgcn_mfma_f32_16x16x32_bf16(fa[m], fb[n], acc[m][n], 0, 0, 0);
    }

    if (MODE == 0 || MODE == 1) {
#pragma unroll
        for (int m = 0; m < 4; ++m) {
#pragma unroll
            for (int n = 0; n < 4; ++n) {
                const int gj = n0 + wc * 64 + n * 16 + lrow;
                const float bj = bias[gj];
#pragma unroll
                for (int r = 0; r < 4; ++r) {
                    const int gi = m0 + wr * 64 + m * 16 + lk * 4 + r;
                    float v = acc[m][n][r] + bj;
                    if (MODE == 0) {
                        v = v > 0.f ? v : expm1f(v);
                        outBf[(size_t)gi * N + gj] = (short)f2bf(v);
                    } else {
                        outF[(size_t)gi * N + gj] = v;
                    }
                }
            }
        }
    } else {
        float colpart[4] = {0.f, 0.f, 0.f, 0.f};
#pragma unroll
        for (int m = 0; m < 4; ++m) {
            float rowpart[4] = {0.f, 0.f, 0.f, 0.f};
#pragma unroll
            for (int n = 0; n < 4; ++n) {
#pragma unroll
                for (int r = 0; r < 4; ++r) {
                    float v = exp2f(acc[m][n][r] * CEXP);
                    rowpart[r] += v;
                    colpart[n] += v;
                }
            }
#pragma unroll
            for (int r = 0; r < 4; ++r) {
                float t = rowpart[r];
                t += __shfl_xor(t, 1);
                t += __shfl_xor(t, 2);
                t += __shfl_xor(t, 4);
                t += __shfl_xor(t, 8);
                if (lrow == 0) {
                    const int gi = m0 + wr * 64 + m * 16 + lk * 4 + r;
                    atomicAdd(&rowsum[gi], t);
                }
            }
        }
        if (WANT_COL) {
#pragma unroll
            for (int n = 0; n < 4; ++n) {
                float t = colpart[n];
                t += __shfl_xor(t, 16);
                t += __shfl_xor(t, 32);
                if (lk == 0) {
                    const int gj = n0 + wc * 64 + n * 16 + lrow;
                    atomicAdd(&colsum[gj], t);
                }
            }
        }
    }
}

// ---------------- row-normalize fp32 -> bf16 ----------------
__global__ void normalize_rows(const float* __restrict__ o, short* __restrict__ an) {
    const int row = blockIdx.x;
    const int t = threadIdx.x;   // 128 threads, 4 elems each
    floatx4 v = ((const floatx4*)(o + ((size_t)row << 9)))[t];
    float ss = v[0]*v[0] + v[1]*v[1] + v[2]*v[2] + v[3]*v[3];
    for (int m = 1; m < 64; m <<= 1) ss += __shfl_xor(ss, m);
    __shared__ float part[2];
    if ((t & 63) == 0) part[t >> 6] = ss;
    __syncthreads();
    const float sc = 1.f / fmaxf(sqrtf(part[0] + part[1]), 1e-12f);
    short4v o4;
    o4[0] = (short)f2bf(v[0] * sc); o4[1] = (short)f2bf(v[1] * sc);
    o4[2] = (short)f2bf(v[2] * sc); o4[3] = (short)f2bf(v[3] * sc);
    ((short4v*)(an + ((size_t)row << 9)))[t] = o4;
}

// ---------------- per-row dot(an1_i, an2_i) ----------------
__global__ void diag_dot(const short* __restrict__ a, const short* __restrict__ b,
                         float* __restrict__ d) {
    const int row = blockIdx.x * 4 + (threadIdx.x >> 6);
    const int lane = threadIdx.x & 63;
    const short8 x = *(const short8*)(a + ((size_t)row << 9) + lane * 8);
    const short8 y = *(const short8*)(b + ((size_t)row << 9) + lane * 8);
    float s = 0.f;
#pragma unroll
    for (int j = 0; j < 8; ++j) s += bf2f(x[j]) * bf2f(y[j]);
    for (int m = 1; m < 64; m <<= 1) s += __shfl_xor(s, m);
    if (lane == 0) d[row] = s;
}

// ---------------- final loss reduction ----------------
__global__ void final_reduce(const float* __restrict__ r1, const float* __restrict__ r2,
                             const float* __restrict__ brow, const float* __restrict__ bcol,
                             const float* __restrict__ d12, float* __restrict__ out) {
    float s = 0.f;
    for (int i = threadIdx.x; i < NND; i += 256) {
        const float den1 = r1[i] + brow[i] - E2;
        const float den2 = r2[i] + bcol[i] - E2;
        s += 0.5f * (logf(den1) + logf(den2)) - d12[i] * TAU_INV;
    }
    for (int m = 1; m < 64; m <<= 1) s += __shfl_xor(s, m);
    __shared__ float part[4];
    const int lane = threadIdx.x & 63, w = threadIdx.x >> 6;
    if (lane == 0) part[w] = s;
    __syncthreads();
    if (threadIdx.x == 0) out[0] = (part[0] + part[1] + part[2] + part[3]) / (float)NND;
}

// ---------------- launch ----------------
extern "C" void kernel_launch(void* const* d_in, const int* in_sizes, int n_in,
                              void* d_out, int out_size, void* d_ws, size_t ws_size,
                              hipStream_t stream) {
    const float* z1 = (const float*)d_in[0];
    const float* z2 = (const float*)d_in[1];
    const float* w1 = (const float*)d_in[3];
    const float* b1 = (const float*)d_in[4];
    const float* w2 = (const float*)d_in[5];
    const float* b2 = (const float*)d_in[6];
    float* out = (float*)d_out;

    char* p = (char*)d_ws;
    const size_t MATB = (size_t)NND * DHID * 2;   // 8 MB bf16 matrix
    short* an1 = (short*)p;  p += MATB;
    short* an2 = (short*)p;  p += MATB;
    short* zb  = (short*)p;  p += MATB;
    short* hb  = (short*)p;  p += MATB;
    float* obuf = (float*)p; p += (size_t)NND * DHID * 4;
    short* w1t = (short*)p;  p += 512 * 512 * 2;
    short* w2t = (short*)p;  p += 512 * 512 * 2;
    float* r1  = (float*)p;  p += NND * 4;
    float* r2  = (float*)p;  p += NND * 4;
    float* brow = (float*)p; p += NND * 4;
    float* bcol = (float*)p; p += NND * 4;
    float* d12 = (float*)p;  p += NND * 4;
    if ((size_t)(p - (char*)d_ws) > ws_size) return;  // workspace too small

    // zero the atomic accumulators (r1,r2,brow,bcol contiguous)
    hipMemsetAsync(r1, 0, (size_t)NND * 4 * 4, stream);

    transpose_cast<<<1024, 256, 0, stream>>>(w1, w1t);
    transpose_cast<<<1024, 256, 0, stream>>>(w2, w2t);

    // projection pipeline z1 -> an1
    cast_bf16<<<2048, 256, 0, stream>>>(z1, zb);
    gemm_nt<0, false><<<dim3(64, 4), 256, 0, stream>>>(zb, w1t, 512, b1, hb, nullptr, nullptr, nullptr);
    gemm_nt<1, false><<<dim3(64, 4), 256, 0, stream>>>(hb, w2t, 512, b2, nullptr, obuf, nullptr, nullptr);
    normalize_rows<<<NND, 128, 0, stream>>>(obuf, an1);

    // projection pipeline z2 -> an2
    cast_bf16<<<2048, 256, 0, stream>>>(z2, zb);
    gemm_nt<0, false><<<dim3(64, 4), 256, 0, stream>>>(zb, w1t, 512, b1, hb, nullptr, nullptr, nullptr);
    gemm_nt<1, false><<<dim3(64, 4), 256, 0, stream>>>(hb, w2t, 512, b2, nullptr, obuf, nullptr, nullptr);
    normalize_rows<<<NND, 128, 0, stream>>>(obuf, an2);

    diag_dot<<<NND / 4, 256, 0, stream>>>(an1, an2, d12);

    // fused similarity row/col sums
    gemm_nt<2, false><<<dim3(64, 64), 256, 0, stream>>>(an1, an1, NND, nullptr, nullptr, nullptr, r1, nullptr);
    gemm_nt<2, false><<<dim3(64, 64), 256, 0, stream>>>(an2, an2, NND, nullptr, nullptr, nullptr, r2, nullptr);
    gemm_nt<2, true ><<<dim3(64, 64), 256, 0, stream>>>(an1, an2, NND, nullptr, nullptr, nullptr, brow, bcol);

    final_reduce<<<1, 256, 0, stream>>>(r1, r2, brow, bcol, d12, out);
}

// Round 2
// 342.945 us; speedup vs baseline: 1.1703x; 1.1703x over previous
//
#include <hip/hip_runtime.h>
#include <hip/hip_bf16.h>

typedef __attribute__((ext_vector_type(8))) short short8;
typedef __attribute__((ext_vector_type(4))) short short4v;
typedef __attribute__((ext_vector_type(4))) float floatx4;

#define NND 8192
#define DHID 512
#define TAU_INV 2.0f
// log2(e)/tau
#define CEXP 2.885390081777927f
#define E2 7.389056098930650f

__device__ inline unsigned short f2bf(float f) {
    union { float f; unsigned u; } v; v.f = f;
    unsigned r = v.u + 0x7FFFu + ((v.u >> 16) & 1u);
    return (unsigned short)(r >> 16);
}
__device__ inline float bf2f(short s) {
    union { unsigned u; float f; } v; v.u = ((unsigned)(unsigned short)s) << 16;
    return v.f;
}

__device__ inline void gload_lds16(const short* g, short* l) {
    __builtin_amdgcn_global_load_lds(
        (const __attribute__((address_space(1))) unsigned int*)g,
        (__attribute__((address_space(3))) unsigned int*)l,
        16, 0, 0);
}

// ---------------- cast / transpose helpers ----------------

__global__ void cast_bf16(const float* __restrict__ in, short* __restrict__ out) {
    int i = blockIdx.x * 256 + threadIdx.x;   // one thread = 8 elems
    floatx4 v0 = ((const floatx4*)in)[2 * i];
    floatx4 v1 = ((const floatx4*)in)[2 * i + 1];
    short8 o;
    o[0] = (short)f2bf(v0[0]); o[1] = (short)f2bf(v0[1]);
    o[2] = (short)f2bf(v0[2]); o[3] = (short)f2bf(v0[3]);
    o[4] = (short)f2bf(v1[0]); o[5] = (short)f2bf(v1[1]);
    o[6] = (short)f2bf(v1[2]); o[7] = (short)f2bf(v1[3]);
    ((short8*)out)[i] = o;
}

// in: [K=512][N=512] row-major; out[n][k] = in[k][n]  (bf16, N x K layout)
__global__ void transpose_cast(const float* __restrict__ in, short* __restrict__ out) {
    int idx = blockIdx.x * 256 + threadIdx.x;
    int n = idx >> 9, k = idx & 511;
    out[(n << 9) + k] = (short)f2bf(in[(k << 9) + n]);
}

// ---------------- fused GEMM (NT): C = A[M,512] * B[N,512]^T ----------------
// MODE 0: +bias, elu, -> bf16 out      (projection layer 1)
// MODE 1: +bias        -> fp32 out     (projection layer 2)
// MODE 2: exp2(c*CEXP) -> atomic row sums (+ col sums if WANT_COL)
// MODE 3: symmetric input (A==B): triangle grid, rowsums get row+col parts
#define BM 128
#define BN 128
#define BK 32

template<int MODE, bool WANT_COL>
__global__ __launch_bounds__(256, 2)
void gemm_nt(const short* __restrict__ A, const short* __restrict__ B, int N,
             const float* __restrict__ bias,
             short* __restrict__ outBf, float* __restrict__ outF,
             float* __restrict__ rowsum, float* __restrict__ colsum)
{
    __shared__ short As[BM * BK];
    __shared__ short Bs[BN * BK];

    const int tid  = threadIdx.x;
    int m0, n0;
    if (MODE == 3) {
        // triangle decode: t -> (bi, bj), bi <= bj, 64 block-rows
        const int t = blockIdx.x;
        int bi = (int)((129.0f - sqrtf(129.0f * 129.0f - 8.0f * (float)t)) * 0.5f);
        while (bi > 0 && bi * 64 - bi * (bi - 1) / 2 > t) --bi;
        while ((bi + 1) * 64 - (bi + 1) * bi / 2 <= t) ++bi;
        const int bj = bi + (t - (bi * 64 - bi * (bi - 1) / 2));
        m0 = bi * BM;
        n0 = bj * BN;
    } else {
        m0 = blockIdx.x * BM;
        n0 = blockIdx.y * BN;
    }
    const int wave = tid >> 6;
    const int lane = tid & 63;
    const int wr   = wave >> 1;        // 0..1 : wave row
    const int wc   = wave & 1;         // 0..1 : wave col
    const int lrow = lane & 15;
    const int lk   = lane >> 4;        // 0..3

    floatx4 acc[4][4];
    floatx4 zero4 = {0.f, 0.f, 0.f, 0.f};
#pragma unroll
    for (int m = 0; m < 4; ++m)
#pragma unroll
        for (int n = 0; n < 4; ++n) acc[m][n] = zero4;

    for (int kt = 0; kt < 512 / BK; ++kt) {
        const int k0 = kt * BK;
        __syncthreads();   // previous iteration's LDS reads done before overwrite
#pragma unroll
        for (int i = 0; i < 2; ++i) {
            const int chunk = i * 256 + tid;          // 16B chunk id, 512 per matrix
            const int row = chunk >> 2;
            const int cb  = (chunk & 3) * 8;
            gload_lds16(A + (size_t)(m0 + row) * 512 + k0 + cb, &As[chunk * 8]);
            gload_lds16(B + (size_t)(n0 + row) * 512 + k0 + cb, &Bs[chunk * 8]);
        }
        __syncthreads();   // compiler drains vmcnt before barrier
        short8 fa[4], fb[4];
#pragma unroll
        for (int m = 0; m < 4; ++m)
            fa[m] = *(const short8*)(&As[(wr * 64 + m * 16 + lrow) * BK + lk * 8]);
#pragma unroll
        for (int n = 0; n < 4; ++n)
            fb[n] = *(const short8*)(&Bs[(wc * 64 + n * 16 + lrow) * BK + lk * 8]);
#pragma unroll
        for (int m = 0; m < 4; ++m)
#pragma unroll
            for (int n = 0; n < 4; ++n)
                acc[m][n] = __builtin_amdgcn_mfma_f32_16x16x32_bf16(fa[m], fb[n], acc[m][n], 0, 0, 0);
    }

    if (MODE == 0 || MODE == 1) {
#pragma unroll
        for (int m = 0; m < 4; ++m) {
#pragma unroll
            for (int n = 0; n < 4; ++n) {
                const int gj = n0 + wc * 64 + n * 16 + lrow;
                const float bj = bias[gj];
#pragma unroll
                for (int r = 0; r < 4; ++r) {
                    const int gi = m0 + wr * 64 + m * 16 + lk * 4 + r;
                    float v = acc[m][n][r] + bj;
                    if (MODE == 0) {
                        v = v > 0.f ? v : expm1f(v);
                        outBf[(size_t)gi * N + gj] = (short)f2bf(v);
                    } else {
                        outF[(size_t)gi * N + gj] = v;
                    }
                }
            }
        }
    } else {
        float colpart[4] = {0.f, 0.f, 0.f, 0.f};
#pragma unroll
        for (int m = 0; m < 4; ++m) {
            float rowpart[4] = {0.f, 0.f, 0.f, 0.f};
#pragma unroll
            for (int n = 0; n < 4; ++n) {
#pragma unroll
                for (int r = 0; r < 4; ++r) {
                    float v = exp2f(acc[m][n][r] * CEXP);
                    rowpart[r] += v;
                    colpart[n] += v;
                }
            }
#pragma unroll
            for (int r = 0; r < 4; ++r) {
                float t = rowpart[r];
                t += __shfl_xor(t, 1);
                t += __shfl_xor(t, 2);
                t += __shfl_xor(t, 4);
                t += __shfl_xor(t, 8);
                if (lrow == 0) {
                    const int gi = m0 + wr * 64 + m * 16 + lk * 4 + r;
                    atomicAdd(&rowsum[gi], t);
                }
            }
        }
        const bool want_col = (MODE == 2) ? WANT_COL : (m0 != n0);
        if (want_col) {
            float* ctgt = (MODE == 3) ? rowsum : colsum;
#pragma unroll
            for (int n = 0; n < 4; ++n) {
                float t = colpart[n];
                t += __shfl_xor(t, 16);
                t += __shfl_xor(t, 32);
                if (lk == 0) {
                    const int gj = n0 + wc * 64 + n * 16 + lrow;
                    atomicAdd(&ctgt[gj], t);
                }
            }
        }
    }
}

// ---------------- row-normalize fp32 -> bf16 ----------------
__global__ void normalize_rows(const float* __restrict__ o, short* __restrict__ an) {
    const int row = blockIdx.x;
    const int t = threadIdx.x;   // 128 threads, 4 elems each
    floatx4 v = ((const floatx4*)(o + ((size_t)row << 9)))[t];
    float ss = v[0]*v[0] + v[1]*v[1] + v[2]*v[2] + v[3]*v[3];
    for (int m = 1; m < 64; m <<= 1) ss += __shfl_xor(ss, m);
    __shared__ float part[2];
    if ((t & 63) == 0) part[t >> 6] = ss;
    __syncthreads();
    const float sc = 1.f / fmaxf(sqrtf(part[0] + part[1]), 1e-12f);
    short4v o4;
    o4[0] = (short)f2bf(v[0] * sc); o4[1] = (short)f2bf(v[1] * sc);
    o4[2] = (short)f2bf(v[2] * sc); o4[3] = (short)f2bf(v[3] * sc);
    ((short4v*)(an + ((size_t)row << 9)))[t] = o4;
}

// ---------------- per-row dot(an1_i, an2_i) ----------------
__global__ void diag_dot(const short* __restrict__ a, const short* __restrict__ b,
                         float* __restrict__ d) {
    const int row = blockIdx.x * 4 + (threadIdx.x >> 6);
    const int lane = threadIdx.x & 63;
    const short8 x = *(const short8*)(a + ((size_t)row << 9) + lane * 8);
    const short8 y = *(const short8*)(b + ((size_t)row << 9) + lane * 8);
    float s = 0.f;
#pragma unroll
    for (int j = 0; j < 8; ++j) s += bf2f(x[j]) * bf2f(y[j]);
    for (int m = 1; m < 64; m <<= 1) s += __shfl_xor(s, m);
    if (lane == 0) d[row] = s;
}

// ---------------- final loss reduction ----------------
__global__ void final_reduce(const float* __restrict__ r1, const float* __restrict__ r2,
                             const float* __restrict__ brow, const float* __restrict__ bcol,
                             const float* __restrict__ d12, float* __restrict__ out) {
    float s = 0.f;
    for (int i = threadIdx.x; i < NND; i += 256) {
        const float den1 = r1[i] + brow[i] - E2;
        const float den2 = r2[i] + bcol[i] - E2;
        s += 0.5f * (logf(den1) + logf(den2)) - d12[i] * TAU_INV;
    }
    for (int m = 1; m < 64; m <<= 1) s += __shfl_xor(s, m);
    __shared__ float part[4];
    const int lane = threadIdx.x & 63, w = threadIdx.x >> 6;
    if (lane == 0) part[w] = s;
    __syncthreads();
    if (threadIdx.x == 0) out[0] = (part[0] + part[1] + part[2] + part[3]) / (float)NND;
}

// ---------------- launch ----------------
extern "C" void kernel_launch(void* const* d_in, const int* in_sizes, int n_in,
                              void* d_out, int out_size, void* d_ws, size_t ws_size,
                              hipStream_t stream) {
    const float* z1 = (const float*)d_in[0];
    const float* z2 = (const float*)d_in[1];
    const float* w1 = (const float*)d_in[3];
    const float* b1 = (const float*)d_in[4];
    const float* w2 = (const float*)d_in[5];
    const float* b2 = (const float*)d_in[6];
    float* out = (float*)d_out;

    char* p = (char*)d_ws;
    const size_t MATB = (size_t)NND * DHID * 2;   // 8 MB bf16 matrix
    short* an1 = (short*)p;  p += MATB;
    short* an2 = (short*)p;  p += MATB;
    short* zb  = (short*)p;  p += MATB;
    short* hb  = (short*)p;  p += MATB;
    float* obuf = (float*)p; p += (size_t)NND * DHID * 4;
    short* w1t = (short*)p;  p += 512 * 512 * 2;
    short* w2t = (short*)p;  p += 512 * 512 * 2;
    float* r1  = (float*)p;  p += NND * 4;
    float* r2  = (float*)p;  p += NND * 4;
    float* brow = (float*)p; p += NND * 4;
    float* bcol = (float*)p; p += NND * 4;
    float* d12 = (float*)p;  p += NND * 4;
    if ((size_t)(p - (char*)d_ws) > ws_size) return;  // workspace too small

    // zero the atomic accumulators (r1,r2,brow,bcol contiguous)
    hipMemsetAsync(r1, 0, (size_t)NND * 4 * 4, stream);

    transpose_cast<<<1024, 256, 0, stream>>>(w1, w1t);
    transpose_cast<<<1024, 256, 0, stream>>>(w2, w2t);

    // projection pipeline z1 -> an1
    cast_bf16<<<2048, 256, 0, stream>>>(z1, zb);
    gemm_nt<0, false><<<dim3(64, 4), 256, 0, stream>>>(zb, w1t, 512, b1, hb, nullptr, nullptr, nullptr);
    gemm_nt<1, false><<<dim3(64, 4), 256, 0, stream>>>(hb, w2t, 512, b2, nullptr, obuf, nullptr, nullptr);
    normalize_rows<<<NND, 128, 0, stream>>>(obuf, an1);

    // projection pipeline z2 -> an2
    cast_bf16<<<2048, 256, 0, stream>>>(z2, zb);
    gemm_nt<0, false><<<dim3(64, 4), 256, 0, stream>>>(zb, w1t, 512, b1, hb, nullptr, nullptr, nullptr);
    gemm_nt<1, false><<<dim3(64, 4), 256, 0, stream>>>(hb, w2t, 512, b2, nullptr, obuf, nullptr, nullptr);
    normalize_rows<<<NND, 128, 0, stream>>>(obuf, an2);

    diag_dot<<<NND / 4, 256, 0, stream>>>(an1, an2, d12);

    // fused similarity row/col sums; S11 & S22 are symmetric -> triangle grid
    gemm_nt<3, false><<<2080, 256, 0, stream>>>(an1, an1, NND, nullptr, nullptr, nullptr, r1, nullptr);
    gemm_nt<3, false><<<2080, 256, 0, stream>>>(an2, an2, NND, nullptr, nullptr, nullptr, r2, nullptr);
    gemm_nt<2, true ><<<dim3(64, 64), 256, 0, stream>>>(an1, an2, NND, nullptr, nullptr, nullptr, brow, bcol);

    final_reduce<<<1, 256, 0, stream>>>(r1, r2, brow, bcol, d12, out);
}